// Round 3
// baseline (217.532 us; speedup 1.0000x reference)
//
#include <hip/hip_runtime.h>
#include <math.h>

#define B_  16
#define L_  2048
#define D_  512
#define K_  7
#define Q_  (B_*L_*D_)   // 16777216 elements per output tensor

// ---------------------------------------------------------------------------
// Kernel A: tiled transpose (B,L,D) -> (B,D,L) for q and k.
// ---------------------------------------------------------------------------
__global__ __launch_bounds__(256) void kA(const float* __restrict__ q,
                                          const float* __restrict__ k,
                                          float* __restrict__ qT,
                                          float* __restrict__ kT) {
  __shared__ float tq[32][33];
  __shared__ float tk[32][33];
  const int l0 = blockIdx.x * 32, d0 = blockIdx.y * 32, b = blockIdx.z;
  const int tx = threadIdx.x, ty = threadIdx.y;       // (32,8)
  const size_t ibase = (size_t)b * L_ * D_;
#pragma unroll
  for (int j = 0; j < 4; ++j) {
    const int l = l0 + ty + 8 * j;
    tq[ty + 8 * j][tx] = q[ibase + (size_t)l * D_ + d0 + tx];
    tk[ty + 8 * j][tx] = k[ibase + (size_t)l * D_ + d0 + tx];
  }
  __syncthreads();
  const size_t obase = (size_t)b * D_ * L_;
#pragma unroll
  for (int j = 0; j < 4; ++j) {
    const int d = d0 + ty + 8 * j;
    qT[obase + (size_t)d * L_ + l0 + tx] = tq[tx][ty + 8 * j];
    kT[obase + (size_t)d * L_ + l0 + tx] = tk[tx][ty + 8 * j];
  }
}

// ---------------------------------------------------------------------------
// Kernel B: 2 channels per block. z=q+ik packed forward FFT per channel;
// Hermitian S1 half-spectrum stored; one packed inverse IFFT(S1+i*S2)
// produces both channels' corr as Re/Im.  Mixed-radix (8,8,8,4) Stockham,
// interleaved float2 complex LDS with unified XOR-swizzle.
// ---------------------------------------------------------------------------
struct cf { float r, i; };
__device__ __forceinline__ cf cadd(cf a, cf b){ return {a.r+b.r, a.i+b.i}; }
__device__ __forceinline__ cf csub(cf a, cf b){ return {a.r-b.r, a.i-b.i}; }
__device__ __forceinline__ cf cmul(cf a, cf b){ return {a.r*b.r - a.i*b.i, a.r*b.i + a.i*b.r}; }
template<bool INV> __device__ __forceinline__ cf rot90(cf x){
  return INV ? cf{-x.i, x.r} : cf{x.i, -x.r};   // * +/- i
}
// unified swizzle on the complex index (float2 elements, 8B each)
__device__ __forceinline__ int swz(int a){ return a ^ (((a >> 4) ^ (a >> 8)) & 15); }
__device__ __forceinline__ cf ldx(const float2* __restrict__ p, int i){
  const float2 v = p[swz(i)]; return {v.x, v.y};
}
__device__ __forceinline__ void stx(float2* __restrict__ p, int i, cf v){
  p[swz(i)] = {v.r, v.i};
}

template<bool INV>
__device__ __forceinline__ void dft8(cf a[8], cf b[8]) {
  const float H = 0.70710678118654752440f;
  cf t0 = cadd(a[0],a[4]), t1 = cadd(a[1],a[5]), t2 = cadd(a[2],a[6]), t3 = cadd(a[3],a[7]);
  cf u0 = csub(a[0],a[4]), u1 = csub(a[1],a[5]), u2 = csub(a[2],a[6]), u3 = csub(a[3],a[7]);
  const cf w1 = INV ? cf{H,  H} : cf{ H, -H};
  const cf w3 = INV ? cf{-H, H} : cf{-H, -H};
  u1 = cmul(u1, w1);
  u2 = rot90<INV>(u2);
  u3 = cmul(u3, w3);
  { cf s0 = cadd(t0,t2), s1 = csub(t0,t2), s2 = cadd(t1,t3), s3 = rot90<INV>(csub(t1,t3));
    b[0]=cadd(s0,s2); b[4]=csub(s0,s2); b[2]=cadd(s1,s3); b[6]=csub(s1,s3); }
  { cf s0 = cadd(u0,u2), s1 = csub(u0,u2), s2 = cadd(u1,u3), s3 = rot90<INV>(csub(u1,u3));
    b[1]=cadd(s0,s2); b[5]=csub(s0,s2); b[3]=cadd(s1,s3); b[7]=csub(s1,s3); }
}

template<int LOG2S, bool INV>
__device__ __forceinline__ void pass8f2(const float2* __restrict__ src,
                                        float2* __restrict__ dst, int tid) {
  const int p = tid >> LOG2S;
  cf a[8], b[8];
#pragma unroll
  for (int l = 0; l < 8; ++l) a[l] = ldx(src, tid + (l << 8));
  dft8<INV>(a, b);
  const float ANG = -0.0030679615757712823f;  // -2*pi/2048
  float sn, cs;
  __sincosf(ANG * (float)(p << LOG2S), &sn, &cs);
  if (INV) sn = -sn;
  const cf w1{cs, sn};
  cf w = w1;
  b[1] = cmul(b[1], w);
#pragma unroll
  for (int k = 2; k < 8; ++k) { w = cmul(w, w1); b[k] = cmul(b[k], w); }
  const int wb = tid + 7 * (p << LOG2S);
#pragma unroll
  for (int k = 0; k < 8; ++k) stx(dst, wb + (k << LOG2S), b[k]);
}

template<bool INV>
__device__ __forceinline__ void pass4f2(const float2* __restrict__ src,
                                        float2* __restrict__ dst, int tid) {
#pragma unroll
  for (int h = 0; h < 2; ++h) {
    const int j = tid + (h << 8);
    cf a0 = ldx(src, j), a1 = ldx(src, j + 512), a2 = ldx(src, j + 1024), a3 = ldx(src, j + 1536);
    cf s0 = cadd(a0,a2), s1 = csub(a0,a2), s2 = cadd(a1,a3), s3 = rot90<INV>(csub(a1,a3));
    stx(dst, j,        cadd(s0,s2));
    stx(dst, j + 512,  cadd(s1,s3));
    stx(dst, j + 1024, csub(s0,s2));
    stx(dst, j + 1536, csub(s1,s3));
  }
}

__device__ __forceinline__ void load_ch(const float* __restrict__ qp,
                                        const float* __restrict__ kp,
                                        float2* __restrict__ A, int tid) {
#pragma unroll
  for (int u = 0; u < 2; ++u) {
    const int i4 = tid + (u << 8);
    const float4 vq = ((const float4*)qp)[i4];
    const float4 vk = ((const float4*)kp)[i4];
    const int base = i4 << 2;
    A[swz(base + 0)] = {vq.x, vk.x};
    A[swz(base + 1)] = {vq.y, vk.y};
    A[swz(base + 2)] = {vq.z, vk.z};
    A[swz(base + 3)] = {vq.w, vk.w};
  }
}

// S[f] = Q[f]*conj(K[f]) from Hermitian split of packed Z; f=0..1023.
// slot 0 packs {S[0].r, S[1024].r} (both real).
__device__ __forceinline__ void spectrum_half(const float2* __restrict__ A,
                                              float2* __restrict__ S1, int tid) {
#pragma unroll
  for (int u = 0; u < 4; ++u) {
    const int f = tid + (u << 8);
    if (f == 0) {
      const cf z0 = ldx(A, 0), zn = ldx(A, 1024);
      S1[0] = {z0.r * z0.i, zn.r * zn.i};
    } else {
      const cf a = ldx(A, f), b = ldx(A, 2048 - f);
      const float qr = 0.5f * (a.r + b.r), qi = 0.5f * (a.i - b.i);
      const float kr = 0.5f * (a.i + b.i), ki = 0.5f * (b.r - a.r);
      S1[f] = {qr * kr + qi * ki, qi * kr - qr * ki};
    }
  }
}

// Z = S1 + i*S2 (full 2048 spectrum) into dst; A holds ch1's packed FFT.
__device__ __forceinline__ void combine(const float2* __restrict__ A,
                                        const float2* __restrict__ S1,
                                        float2* __restrict__ dst, int tid) {
#pragma unroll
  for (int u = 0; u < 4; ++u) {
    const int f = tid + (u << 8);
    if (f == 0) {
      const cf z0 = ldx(A, 0), zn = ldx(A, 1024);
      const float s2_0 = z0.r * z0.i, s2_n = zn.r * zn.i;
      const float2 s1 = S1[0];
      stx(dst, 0,    {s1.x, s2_0});
      stx(dst, 1024, {s1.y, s2_n});
    } else {
      const cf a = ldx(A, f), b = ldx(A, 2048 - f);
      const float qr = 0.5f * (a.r + b.r), qi = 0.5f * (a.i - b.i);
      const float kr = 0.5f * (a.i + b.i), ki = 0.5f * (b.r - a.r);
      const float s2r = qr * kr + qi * ki, s2i = qi * kr - qr * ki;
      const float2 s1 = S1[f];
      stx(dst, f,        {s1.x - s2i,  s1.y + s2r});
      stx(dst, 2048 - f, {s1.x + s2i, -s1.y + s2r});
    }
  }
}

__device__ __forceinline__ void store2(const float2* __restrict__ Bb,
                                       float* __restrict__ c0,
                                       float* __restrict__ c1, int tid) {
  const float inv = 1.0f / (float)L_;
#pragma unroll
  for (int u = 0; u < 2; ++u) {
    const int i4 = tid + (u << 8);
    const int base = i4 << 2;
    const float2 z0 = Bb[swz(base + 0)];
    const float2 z1 = Bb[swz(base + 1)];
    const float2 z2 = Bb[swz(base + 2)];
    const float2 z3 = Bb[swz(base + 3)];
    ((float4*)c0)[i4] = make_float4(z0.x*inv, z1.x*inv, z2.x*inv, z3.x*inv);
    ((float4*)c1)[i4] = make_float4(z0.y*inv, z1.y*inv, z2.y*inv, z3.y*inv);
  }
}

__global__ __launch_bounds__(256) void kB(const float* __restrict__ qT,
                                          const float* __restrict__ kT,
                                          float* __restrict__ corrT) {
  __shared__ float2 A[L_];        // 16 KiB
  __shared__ float2 Bb[L_];       // 16 KiB
  __shared__ float2 S1[L_ / 2];   //  8 KiB  (total 40 KiB -> 4 blocks/CU)
  const int tid = threadIdx.x;
  const size_t row0 = (size_t)(blockIdx.x * 2) * L_;
  const size_t row1 = row0 + L_;

  // ---- channel 0 forward ----
  load_ch(qT + row0, kT + row0, A, tid);  __syncthreads();
  pass8f2<0, false>(A, Bb, tid);          __syncthreads();
  pass8f2<3, false>(Bb, A, tid);          __syncthreads();
  pass8f2<6, false>(A, Bb, tid);          __syncthreads();
  pass4f2<false>(Bb, A, tid);             __syncthreads();
  spectrum_half(A, S1, tid);              __syncthreads();

  // ---- channel 1 forward ----
  load_ch(qT + row1, kT + row1, A, tid);  __syncthreads();
  pass8f2<0, false>(A, Bb, tid);          __syncthreads();
  pass8f2<3, false>(Bb, A, tid);          __syncthreads();
  pass8f2<6, false>(A, Bb, tid);          __syncthreads();
  pass4f2<false>(Bb, A, tid);             __syncthreads();

  // ---- packed inverse: Z = S1 + i*S2 ----
  combine(A, S1, Bb, tid);                __syncthreads();
  pass8f2<0, true>(Bb, A, tid);           __syncthreads();
  pass8f2<3, true>(A, Bb, tid);           __syncthreads();
  pass8f2<6, true>(Bb, A, tid);           __syncthreads();
  pass4f2<true>(A, Bb, tid);              __syncthreads();

  store2(Bb, corrT + row0, corrT + row1, tid);
}

// ---------------------------------------------------------------------------
// Kernel C: transpose corrT (B,D,L) -> corr_out (B,L,D) + per-(b,dtile) sums.
// ---------------------------------------------------------------------------
__global__ __launch_bounds__(256) void kC(const float* __restrict__ corrT,
                                          float* __restrict__ corrOut,
                                          float* __restrict__ partial) {
  __shared__ float t[32][33];
  const int t0 = blockIdx.x * 32, d0 = blockIdx.y * 32, b = blockIdx.z;
  const int tx = threadIdx.x, ty = threadIdx.y;       // (32,8)
#pragma unroll
  for (int j = 0; j < 4; ++j) {
    const int d = d0 + ty + 8 * j;
    t[ty + 8 * j][tx] = corrT[((size_t)b * D_ + d) * L_ + t0 + tx];
  }
  __syncthreads();
#pragma unroll
  for (int j = 0; j < 4; ++j) {
    const int tt = t0 + ty + 8 * j;
    corrOut[((size_t)b * L_ + tt) * D_ + d0 + tx] = t[tx][ty + 8 * j];
  }
  if (ty == 0) {
    float s = 0.f;
#pragma unroll
    for (int i = 0; i < 32; ++i) s += t[i][tx];
    partial[((size_t)b * 16 + blockIdx.y) * L_ + t0 + tx] = s;
  }
}

// ---------------------------------------------------------------------------
// Kernel D0: reduce partial[256][L] -> g[L]  (32 blocks, deterministic)
// ---------------------------------------------------------------------------
__global__ __launch_bounds__(256) void kD0(const float* __restrict__ partial,
                                           float* __restrict__ g) {
  __shared__ float red[4][64];
  const int tl = threadIdx.x & 63, rg = threadIdx.x >> 6;
  const int tau = blockIdx.x * 64 + tl;
  float s = 0.f;
  for (int i = rg; i < 256; i += 4) s += partial[(size_t)i * L_ + tau];
  red[rg][tl] = s;
  __syncthreads();
  if (rg == 0) g[tau] = red[0][tl] + red[1][tl] + red[2][tl] + red[3][tl];
}

// ---------------------------------------------------------------------------
// Kernel D1: top-7 on g[L]; per-b softmax weights. Single small block.
// ---------------------------------------------------------------------------
__global__ __launch_bounds__(256) void kD1(const float* __restrict__ gin,
                                           const float* __restrict__ partial,
                                           int* __restrict__ oidx,
                                           float* __restrict__ ow) {
  __shared__ float g[L_];
  __shared__ float rv[256];
  __shared__ int   ri[256];
  __shared__ int   sidx[K_];
  const int tid = threadIdx.x;
#pragma unroll
  for (int u = 0; u < 8; ++u) g[tid + u * 256] = gin[tid + u * 256];
  __syncthreads();

  for (int it = 0; it < K_; ++it) {
    float bv = -1e30f; int bix = 1 << 30;
#pragma unroll
    for (int u = 0; u < 8; ++u) {
      const int tau = tid + u * 256;
      const float vv = g[tau];
      if (vv > bv || (vv == bv && tau < bix)) { bv = vv; bix = tau; }
    }
    rv[tid] = bv; ri[tid] = bix;
    __syncthreads();
    for (int off = 128; off > 0; off >>= 1) {
      if (tid < off) {
        const float v2 = rv[tid + off]; const int i2 = ri[tid + off];
        if (v2 > rv[tid] || (v2 == rv[tid] && i2 < ri[tid])) {
          rv[tid] = v2; ri[tid] = i2;
        }
      }
      __syncthreads();
    }
    if (tid == 0) { sidx[it] = ri[0]; g[ri[0]] = -3e38f; }
    __syncthreads();
  }

  if (tid < B_) {
    const int b = tid;
    float m[K_]; float mx = -1e30f;
    for (int kk = 0; kk < K_; ++kk) {
      float s = 0.f;
      for (int dt = 0; dt < 16; ++dt)
        s += partial[((size_t)b * 16 + dt) * L_ + sidx[kk]];
      m[kk] = s * (1.0f / 512.0f);
      mx = fmaxf(mx, m[kk]);
    }
    float sum = 0.f;
    for (int kk = 0; kk < K_; ++kk) { m[kk] = expf(m[kk] - mx); sum += m[kk]; }
    const float inv = 1.0f / sum;
    for (int kk = 0; kk < K_; ++kk) ow[b * K_ + kk] = m[kk] * inv;
  }
  if (tid < K_) oidx[tid] = sidx[tid];
}

// ---------------------------------------------------------------------------
// Kernel E: out[b,l,:] = sum_k w[b,k] * v[b, (l+idx[k])%L, :]   (float4)
// ---------------------------------------------------------------------------
__global__ __launch_bounds__(256) void kE(const float4* __restrict__ v4,
                                          const float* __restrict__ w,
                                          const int* __restrict__ idx,
                                          float4* __restrict__ out4) {
  const int bx = blockIdx.x;
  const int b  = bx >> 10;
  const int l  = ((bx & 1023) << 1) | (threadIdx.x >> 7);
  const int j  = threadIdx.x & 127;

  float ww[K_]; int rr[K_];
#pragma unroll
  for (int kk = 0; kk < K_; ++kk) {
    ww[kk] = w[b * K_ + kk];
    int r = l + idx[kk];
    if (r >= L_) r -= L_;
    rr[kk] = r;
  }
  const size_t vb = (size_t)b * L_ * 128;
  float4 acc = make_float4(0.f, 0.f, 0.f, 0.f);
#pragma unroll
  for (int kk = 0; kk < K_; ++kk) {
    const float4 vv = v4[vb + (size_t)rr[kk] * 128 + j];
    acc.x += ww[kk] * vv.x; acc.y += ww[kk] * vv.y;
    acc.z += ww[kk] * vv.z; acc.w += ww[kk] * vv.w;
  }
  out4[vb + (size_t)l * 128 + j] = acc;
}

// ---------------------------------------------------------------------------
extern "C" void kernel_launch(void* const* d_in, const int* in_sizes, int n_in,
                              void* d_out, int out_size, void* d_ws, size_t ws_size,
                              hipStream_t stream) {
  const float* q = (const float*)d_in[0];
  const float* k = (const float*)d_in[1];
  const float* v = (const float*)d_in[2];

  float* out     = (float*)d_out;        // final out  [0, Q_)
  float* corrOut = out + Q_;             // final corr [Q_, 2Q_)
  float* qT = out;                       // scratch: dead before kE overwrites
  float* kT = corrOut;                   // scratch: dead before kC overwrites

  float* corrT   = (float*)d_ws;                 // Q_ floats
  float* partial = corrT + Q_;                   // 524288 floats
  int*   oidx    = (int*)(partial + (size_t)B_ * 16 * L_);
  float* ow      = (float*)(oidx + 16);
  float* g2048   = corrT;                        // corrT dead after kC

  const dim3 thr(32, 8);
  kA<<<dim3(L_ / 32, D_ / 32, B_), thr, 0, stream>>>(q, k, qT, kT);
  kB<<<(B_ * D_) / 2, 256, 0, stream>>>(qT, kT, corrT);
  kC<<<dim3(L_ / 32, D_ / 32, B_), thr, 0, stream>>>(corrT, corrOut, partial);
  kD0<<<32, 256, 0, stream>>>(partial, g2048);
  kD1<<<1, 256, 0, stream>>>(g2048, partial, oidx, ow);
  kE<<<(B_ * L_) / 2, 256, 0, stream>>>((const float4*)v, ow, oidx, (float4*)out);
}